// Round 2
// baseline (574.286 us; speedup 1.0000x reference)
//
#include <hip/hip_runtime.h>
#include <cstdint>
#include <cstddef>

// DigitCapsules routing: B=256, R=1152, C=10, IC=8, OC=16, 3 iters.
// R1 structure (4 launches, deterministic, no atomics):
//   1. caps_u:   u[b][c][r][o] (bf16, 94 MB). x staged in LDS (read once),
//                W in regs (8-deep b-loop).
//   2. caps_fused mode0: s1 = 0.1*sum_r u -> v1 -> vsum := v1       (1 u-read)
//   3. caps_fused mode1: logits=u.vsum -> softmax_c -> s2 -> vsum+=v2 (1 u-read)
//   4. caps_fused mode2: same -> v3 -> d_out                         (1 u-read)
// Key algebra: routing logits are linear in v (b_t = u.(v1+..+v_{t-1})), so a
// running vsum replaces the logit accumulator, and cc+route fuse into one pass.
#define NB 256
#define NR 1152
#define NC 10
#define NI 8
#define NO 16

// pack two fp32 into one uint32 of bf16s (round-to-nearest-even)
static __device__ __forceinline__ uint32_t bf16_pack2(float lo, float hi) {
    uint32_t vl = __float_as_uint(lo);
    vl = vl + 0x7FFFu + ((vl >> 16) & 1u);
    uint32_t vh = __float_as_uint(hi);
    vh = vh + 0x7FFFu + ((vh >> 16) & 1u);
    return (vl >> 16) | (vh & 0xFFFF0000u);
}

// -------------------------------------------------------------------------
// u-compute. Block = (b-group of 8) x (r-tile of 32) covering ALL 10 c.
// 320 threads: t = c*32 + r_local. x staged in LDS (each x elem fetched from
// HBM exactly once); W[r][c] (128 floats) cached in registers across b-loop.
// grid: 32 b-groups * 36 r-tiles = 1152 blocks
__global__ __launch_bounds__(320) void caps_u_kernel(
    const float* __restrict__ x, const float* __restrict__ W,
    uint32_t* __restrict__ u)
{
    const int t  = threadIdx.x;
    const int c  = t >> 5;        // 0..9
    const int rl = t & 31;        // 0..31
    const int bg = blockIdx.x / 36;   // 0..31
    const int rt = blockIdx.x - bg * 36;
    const int r  = rt * 32 + rl;

    __shared__ float xs[8][32][9];    // +1 pad: kills 4-way LDS bank conflict

    // cooperative x stage: x[b][r][i] flat = b*9216 + rt*256 + (rl*8+i)
    for (int k = t; k < 2048; k += 320) {
        const int bi = k >> 8, rem = k & 255;
        xs[bi][rem >> 3][rem & 7] =
            x[(size_t)(bg * 8 + bi) * 9216 + rt * 256 + rem];
    }

    // W[r][c][i][o]: 128 contiguous floats -> 32 float4 in regs
    const float4* wp = (const float4*)(W + ((size_t)r * NC + c) * (NI * NO));
    float4 w[32];
#pragma unroll
    for (int k = 0; k < 32; ++k) w[k] = wp[k];

    __syncthreads();

    for (int bi = 0; bi < 8; ++bi) {
        const int b = bg * 8 + bi;
        float xi[8];
#pragma unroll
        for (int i = 0; i < 8; ++i) xi[i] = xs[bi][rl][i];
        float4 a0 = {0,0,0,0}, a1 = {0,0,0,0}, a2 = {0,0,0,0}, a3 = {0,0,0,0};
#pragma unroll
        for (int i = 0; i < 8; ++i) {
            const float xv = xi[i];
            const float4 w0 = w[i*4+0], w1 = w[i*4+1], w2 = w[i*4+2], w3 = w[i*4+3];
            a0.x += xv*w0.x; a0.y += xv*w0.y; a0.z += xv*w0.z; a0.w += xv*w0.w;
            a1.x += xv*w1.x; a1.y += xv*w1.y; a1.z += xv*w1.z; a1.w += xv*w1.w;
            a2.x += xv*w2.x; a2.y += xv*w2.y; a2.z += xv*w2.z; a2.w += xv*w2.w;
            a3.x += xv*w3.x; a3.y += xv*w3.y; a3.z += xv*w3.z; a3.w += xv*w3.w;
        }
        uint4 s0, s1;
        s0.x = bf16_pack2(a0.x, a0.y); s0.y = bf16_pack2(a0.z, a0.w);
        s0.z = bf16_pack2(a1.x, a1.y); s0.w = bf16_pack2(a1.z, a1.w);
        s1.x = bf16_pack2(a2.x, a2.y); s1.y = bf16_pack2(a2.z, a2.w);
        s1.z = bf16_pack2(a3.x, a3.y); s1.w = bf16_pack2(a3.z, a3.w);
        uint4* up = (uint4*)(u + (((size_t)b * NC + c) * NR + r) * 8);
        up[0] = s0;
        up[1] = s1;
    }
}

// -------------------------------------------------------------------------
// Fused routing iteration: one block per b, 512 threads = 128 r-lanes x 4
// o-quads, 9 r-sweeps. Reads u once; does logits -> softmax_c -> weighted
// r-reduction -> squash -> vsum/out, all in-block (no partials kernel).
// mode 0: cc=0.1 uniform, vsum  = v
// mode 1: cc=softmax(u.vsum),  vsum += v
// mode 2: cc=softmax(u.vsum),  out  = v
__global__ __launch_bounds__(512) void caps_fused_kernel(
    const uint32_t* __restrict__ u, float* __restrict__ vsum,
    float* __restrict__ out, const int mode)
{
    const int b  = blockIdx.x;
    const int t  = threadIdx.x;
    const int oq = t & 3;     // o-quad: o = oq*4..oq*4+3
    const int rl = t >> 2;    // 0..127

    __shared__ float vs[160];
    __shared__ float sred[8][160];
    __shared__ float sfin[160];
    __shared__ float sscale[10];

    if (mode != 0 && t < 160) vs[t] = vsum[b * 160 + t];
    __syncthreads();

    float vreg[10][4];
    if (mode != 0) {
#pragma unroll
        for (int c = 0; c < 10; ++c)
#pragma unroll
            for (int j = 0; j < 4; ++j) vreg[c][j] = vs[c * 16 + oq * 4 + j];
    }

    float acc[10][4];
#pragma unroll
    for (int c = 0; c < 10; ++c)
#pragma unroll
        for (int j = 0; j < 4; ++j) acc[c][j] = 0.f;

    // u words: row (b,c,r) = 8 uint32; this thread's quad = uint2 at index oq
    const uint2* ub = (const uint2*)(u + (size_t)b * NC * NR * 8);

    for (int k = 0; k < 9; ++k) {
        const int r = k * 128 + rl;
        uint2 q[10];
#pragma unroll
        for (int c = 0; c < 10; ++c) q[c] = ub[((size_t)c * NR + r) * 4 + oq];
        float uu[10][4];
#pragma unroll
        for (int c = 0; c < 10; ++c) {
            uu[c][0] = __uint_as_float(q[c].x << 16);
            uu[c][1] = __uint_as_float(q[c].x & 0xFFFF0000u);
            uu[c][2] = __uint_as_float(q[c].y << 16);
            uu[c][3] = __uint_as_float(q[c].y & 0xFFFF0000u);
        }
        float wgt[10];
        if (mode != 0) {
            float lg[10];
#pragma unroll
            for (int c = 0; c < 10; ++c) {
                float d = uu[c][0] * vreg[c][0] + uu[c][1] * vreg[c][1]
                        + uu[c][2] * vreg[c][2] + uu[c][3] * vreg[c][3];
                lg[c] = d;
            }
            // full o-dot: combine the 4 o-quad lanes (tid bits 0,1)
#pragma unroll
            for (int c = 0; c < 10; ++c) {
                lg[c] += __shfl_xor(lg[c], 1);
                lg[c] += __shfl_xor(lg[c], 2);
            }
            float m = lg[0];
#pragma unroll
            for (int c = 1; c < 10; ++c) m = fmaxf(m, lg[c]);
            float ssum = 0.f;
#pragma unroll
            for (int c = 0; c < 10; ++c) { wgt[c] = __expf(lg[c] - m); ssum += wgt[c]; }
            const float inv = 1.f / ssum;
#pragma unroll
            for (int c = 0; c < 10; ++c) wgt[c] *= inv;
        } else {
#pragma unroll
            for (int c = 0; c < 10; ++c) wgt[c] = 1.f;   // 0.1 folded in later
        }
#pragma unroll
        for (int c = 0; c < 10; ++c)
#pragma unroll
            for (int j = 0; j < 4; ++j) acc[c][j] += wgt[c] * uu[c][j];
    }

    // reduce over the 16 r-lanes within each wave (tid bits 2..5)
#pragma unroll
    for (int off = 4; off <= 32; off <<= 1) {
#pragma unroll
        for (int c = 0; c < 10; ++c)
#pragma unroll
            for (int j = 0; j < 4; ++j) acc[c][j] += __shfl_xor(acc[c][j], off);
    }
    const int wv = t >> 6;  // 8 waves
    if ((t & 63) < 4) {     // lanes 0..3 hold (all c, their o-quad)
#pragma unroll
        for (int c = 0; c < 10; ++c)
#pragma unroll
            for (int j = 0; j < 4; ++j)
                sred[wv][c * 16 + oq * 4 + j] = acc[c][j];
    }
    __syncthreads();
    if (t < 160) {
        float s = 0.f;
#pragma unroll
        for (int w = 0; w < 8; ++w) s += sred[w][t];
        if (mode == 0) s *= 0.1f;
        sfin[t] = s;
    }
    __syncthreads();
    if (t < 10) {
        float n2 = 0.f;
#pragma unroll
        for (int o = 0; o < 16; ++o) { const float v = sfin[t * 16 + o]; n2 += v * v; }
        const float nrm = sqrtf(n2);
        sscale[t] = n2 / (1.f + n2) / (nrm + 1e-8f);
    }
    __syncthreads();
    if (t < 160) {
        const float v = sscale[t >> 4] * sfin[t];
        if (mode == 0)      vsum[b * 160 + t] = v;
        else if (mode == 1) vsum[b * 160 + t] = vs[t] + v;
        else                out[b * 160 + t] = v;
    }
}

// -------------------------------------------------------------------------
extern "C" void kernel_launch(void* const* d_in, const int* in_sizes, int n_in,
                              void* d_out, int out_size, void* d_ws, size_t ws_size,
                              hipStream_t stream) {
    const float* x = (const float*)d_in[0];   // [256,1152,8]
    const float* W = (const float*)d_in[1];   // [1,1152,10,8,16]
    float* out = (float*)d_out;               // [256,10,16]

    // workspace: u bf16 [B][C][R][O] = 94,371,840 B ; vsum f32 163,840 B
    uint8_t*  ws  = (uint8_t*)d_ws;
    uint32_t* u   = (uint32_t*)ws;
    float*    vsm = (float*)(ws + 94371840u);

    caps_u_kernel    <<<1152, 320, 0, stream>>>(x, W, u);
    caps_fused_kernel<<< 256, 512, 0, stream>>>(u, vsm, nullptr, 0);
    caps_fused_kernel<<< 256, 512, 0, stream>>>(u, vsm, nullptr, 1);
    caps_fused_kernel<<< 256, 512, 0, stream>>>(u, vsm, out,     2);
}

// Round 3
// 308.212 us; speedup vs baseline: 1.8633x; 1.8633x over previous
//
#include <hip/hip_runtime.h>
#include <cstdint>
#include <cstddef>

// DigitCapsules routing: B=256, R=1152, C=10, IC=8, OC=16, 3 iters.
// R3 design: NEVER materialize u (94 MB). Each routing pass recomputes
// u[b,r,c,o] = x[b,r,:].W[r,c,:,o] on the fly:
//   block = (r-chunk of 16) x (b-tile of 32), 256 thr = 16 r-lanes x 16 o-lanes
//   W slice for (r, all c, all i, my o) = 80 floats IN REGISTERS, reused
//   across the 32-b loop. x tile (16 KB) + vsum tile (20 KB) in LDS.
//   logits via 16-lane o-shuffles; softmax per (b,r); per-(b,c,o) partial
//   sums over the 4 in-wave r-lanes via shuffles, then ONE coalesced
//   atomicAdd stream into s[b][c][o] (160 KB). Tiny squash kernel per iter.
// Logits are linear in v: b_t = u.(v1+..+v_{t-1}) -> running vsum, so each
// iteration is exactly one pass. HBM/pass ~ x 9.4 MB + W (L2/L3-hot).
#define NB 256
#define NR 1152
#define NC 10
#define NI 8
#define NO 16
#define RC 16     // r per block
#define BT 32     // b per block
#define NBT 8     // b tiles
// grid = (NR/RC) * NBT = 72*8 = 576 blocks

// mode 0: uniform coupling 0.1 (iter 1, no logits). mode 1: cc=softmax(u.vsum)
__global__ __launch_bounds__(256) void caps_pass_kernel(
    const float* __restrict__ x, const float* __restrict__ W,
    const float* __restrict__ vsum, float* __restrict__ s, const int mode)
{
    const int bt = blockIdx.x & (NBT - 1);
    const int ch = blockIdx.x >> 3;
    const int b0 = bt * BT;
    const int r0 = ch * RC;
    const int t  = threadIdx.x;
    const int rl = t >> 4;    // 0..15 ; wave w holds rl in [4w, 4w+4)
    const int o  = t & 15;
    const int rq = rl & 3;    // r-lane within wave

    __shared__ float xs[BT][RC][NI];    // 16 KB, x[b0+bi][r0+rl][i]
    __shared__ float vss[BT][NO][NC];   // 20 KB, transposed: [bi][o][c]

    // ---- W slice into registers: W[r][c][i][o], my (r, o), all (c,i) ----
    const int r = r0 + rl;
    const float* wp = W + (size_t)r * (NC * NI * NO) + o;
    float w[NC][NI];
#pragma unroll
    for (int c = 0; c < NC; ++c)
#pragma unroll
        for (int i = 0; i < NI; ++i)
            w[c][i] = wp[(c * NI + i) * NO];     // 16 consecutive lanes/64B

    // ---- stage x tile (coalesced float4) ----
    {
        const float4* xg = (const float4*)x;     // row (b,r) = 2 float4
        for (int k = t; k < BT * RC * 2; k += 256) {
            const int bi = k >> 5, rem = k & 31;
            const int rr = rem >> 1, hf = rem & 1;
            const float4 v = xg[((size_t)(b0 + bi) * NR + r0 + rr) * 2 + hf];
            float* dst = &xs[bi][rr][hf * 4];
            dst[0] = v.x; dst[1] = v.y; dst[2] = v.z; dst[3] = v.w;
        }
    }
    // ---- stage vsum tile, transposed to [bi][o][c] ----
    if (mode != 0) {
        for (int k = t; k < BT * 160; k += 256) {
            const int bi = k / 160, j = k - bi * 160;
            vss[bi][j & 15][j >> 4] = vsum[(size_t)(b0 + bi) * 160 + j];
        }
    }
    __syncthreads();

    for (int bi = 0; bi < BT; ++bi) {
        // x row for (b0+bi, r): 16 o-lanes broadcast-read the same 32 B
        const float4* xp = (const float4*)&xs[bi][rl][0];
        const float4 xa = xp[0], xb = xp[1];
        const float xr[8] = {xa.x, xa.y, xa.z, xa.w, xb.x, xb.y, xb.z, xb.w};

        // u[c] for my (r, o): 10 independent 8-FMA chains on registers
        float uu[NC];
#pragma unroll
        for (int c = 0; c < NC; ++c) {
            float a = 0.f;
#pragma unroll
            for (int i = 0; i < NI; ++i) a += xr[i] * w[c][i];
            uu[c] = a;
        }

        float wgt[NC];
        if (mode != 0) {
            float lg[NC];
#pragma unroll
            for (int c = 0; c < NC; ++c) lg[c] = uu[c] * vss[bi][o][c];
            // full o-dot: butterfly over the 16 o-lanes (in-wave)
#pragma unroll
            for (int c = 0; c < NC; ++c) {
                lg[c] += __shfl_xor(lg[c], 1);
                lg[c] += __shfl_xor(lg[c], 2);
                lg[c] += __shfl_xor(lg[c], 4);
                lg[c] += __shfl_xor(lg[c], 8);
            }
            float m = lg[0];
#pragma unroll
            for (int c = 1; c < NC; ++c) m = fmaxf(m, lg[c]);
            float ssum = 0.f;
#pragma unroll
            for (int c = 0; c < NC; ++c) { wgt[c] = __expf(lg[c] - m); ssum += wgt[c]; }
            const float inv = 1.f / ssum;
#pragma unroll
            for (int c = 0; c < NC; ++c) wgt[c] *= inv;
        } else {
#pragma unroll
            for (int c = 0; c < NC; ++c) wgt[c] = 0.1f;
        }

        // s-contrib for my o; reduce over the 4 in-wave r-lanes
        float ct[NC];
#pragma unroll
        for (int c = 0; c < NC; ++c) {
            float v = wgt[c] * uu[c];
            v += __shfl_xor(v, 16);
            v += __shfl_xor(v, 32);
            ct[c] = v;
        }
        if (rq == 0) {   // 16 o-lanes per wave: coalesced 64 B atomic bursts
            float* sb = s + (size_t)(b0 + bi) * 160;
#pragma unroll
            for (int c = 0; c < NC; ++c) atomicAdd(&sb[c * 16 + o], ct[c]);
        }
    }
}

// squash + vsum bookkeeping. grid=256 (b), 192 threads (160 active).
// mode 0: vsum = v ; mode 1: vsum += v ; mode 2: out = v
__global__ __launch_bounds__(192) void caps_squash_kernel(
    const float* __restrict__ s, float* __restrict__ vsum,
    float* __restrict__ out, const int mode)
{
    const int b = blockIdx.x;
    const int t = threadIdx.x;
    if (t >= 160) return;               // t = c*16 + o, 16-lane groups
    const float sv = s[b * 160 + t];
    float n2 = sv * sv;
    n2 += __shfl_xor(n2, 1);
    n2 += __shfl_xor(n2, 2);
    n2 += __shfl_xor(n2, 4);
    n2 += __shfl_xor(n2, 8);
    const float nrm   = sqrtf(n2);
    const float scale = n2 / (1.f + n2) / (nrm + 1e-8f);
    const float v = scale * sv;
    if (mode == 0)      vsum[b * 160 + t] = v;
    else if (mode == 1) vsum[b * 160 + t] += v;
    else                out[b * 160 + t] = v;
}

// -------------------------------------------------------------------------
extern "C" void kernel_launch(void* const* d_in, const int* in_sizes, int n_in,
                              void* d_out, int out_size, void* d_ws, size_t ws_size,
                              hipStream_t stream) {
    const float* x = (const float*)d_in[0];   // [256,1152,8]
    const float* W = (const float*)d_in[1];   // [1,1152,10,8,16]
    float* out = (float*)d_out;               // [256,10,16]

    // workspace: s1,s2,s3 (160 KB each, atomic targets) + vsum (160 KB)
    uint8_t* ws = (uint8_t*)d_ws;
    float* s1  = (float*)(ws);
    float* s2  = (float*)(ws + 163840u);
    float* s3  = (float*)(ws + 2u * 163840u);
    float* vsm = (float*)(ws + 3u * 163840u);

    hipMemsetAsync(ws, 0, 3u * 163840u, stream);
    const int grid = (NR / RC) * NBT;  // 576
    caps_pass_kernel  <<<grid, 256, 0, stream>>>(x, W, vsm, s1, 0);
    caps_squash_kernel<<< 256, 192, 0, stream>>>(s1, vsm, nullptr, 0);
    caps_pass_kernel  <<<grid, 256, 0, stream>>>(x, W, vsm, s2, 1);
    caps_squash_kernel<<< 256, 192, 0, stream>>>(s2, vsm, nullptr, 1);
    caps_pass_kernel  <<<grid, 256, 0, stream>>>(x, W, vsm, s3, 1);
    caps_squash_kernel<<< 256, 192, 0, stream>>>(s3, nullptr, out, 2);
}